// Round 7
// baseline (353.639 us; speedup 1.0000x reference)
//
#include <hip/hip_runtime.h>
#include <math.h>

// R13: R12 with the loadX stride bug fixed (s*512 -> s*256).
// R12 crashed: a CPSG=8 stage covers 256 floats/token but loadX strode 512
// floats/stage -> OOB reads from stage 4 on -> page fault. Deposit/read maps
// were correct; only the stride was wrong.
// Design (from R12): 8 chunks/stage, 8 stages -> half of R11's 16 stall
// windows at the same 16 waves/CU occupancy. x(s+1) issued right after B so
// its in-flight time spans the 48-MFMA section. Non-draining barriers
// (lgkmcnt(0)+s_barrier; vmcnt stays counted).
// Numerics byte-identical to R6..R11: same chunk order 0..63, same per-chunk
// MFMA chain, seg fold after chunk 31 (s==3), f64 combine, f64 softplus,
// verbatim epilogue. d_ws: 1 MB (wt3 only).

typedef _Float16 f16x8 __attribute__((ext_vector_type(8)));
typedef _Float16 f16x4 __attribute__((ext_vector_type(4)));
typedef float f32x4 __attribute__((ext_vector_type(4)));

constexpr int ND = 2048, NE = 64, NK = 8, NTOK = 16384;
constexpr int KC   = 32;            // k per chunk (one MFMA K)
constexpr int NCHT = ND / KC;       // 64 chunks
constexpr int CPSG = 8;             // chunks per stage
constexpr int NSTG = NCHT / CPSG;   // 8 stages
constexpr int HSTG = NSTG / 2;      // numeric K-split boundary (after stage 3)
constexpr int MTOK = 16;            // tokens per block
constexpr int ZROW = 132;           // padded fp32 LDS row for epilogue
constexpr int STG_F16 = CPSG * MTOK * 64;   // 8192 f16 = 16 KB per buffer
constexpr int XPS = CPSG * KC;      // floats per token per stage = 256

// ---- prep: W1|W2 -> f16 hi / lo*2^11 planes in MFMA B-fragment order (unchanged).
__global__ void prep_w(const float* __restrict__ W1, const float* __restrict__ W2,
                       _Float16* __restrict__ wt3) {
    const int g    = blockIdx.x * 256 + threadIdx.x;   // 0..32767
    const int cg   = g >> 9;
    const int rem  = g & 511;
    const int t    = rem >> 6;
    const int lane = rem & 63;
    const int col  = lane & 15, q = lane >> 4;
    const int n    = t * 16 + col;
    const float* W = (t < 4) ? W1 : W2;
    const int cn   = n & 63;
    _Float16 h[8], l[8];
    #pragma unroll
    for (int j = 0; j < 8; ++j) {
        const float v = W[(size_t)(cg * 32 + q * 8 + j) * 64 + cn];
        const _Float16 hh = (_Float16)v;
        h[j] = hh;
        l[j] = (_Float16)((v - (float)hh) * 2048.0f);
    }
    *(f16x8*)&wt3[((size_t)(cg * 2 + 0) * 8 + t) * 512 + lane * 8] = *(f16x8*)h;
    *(f16x8*)&wt3[((size_t)(cg * 2 + 1) * 8 + t) * 512 + lane * 8] = *(f16x8*)l;
}

__device__ __forceinline__ void split4(const float4 v, f16x4& hh, f16x4& ll) {
    const _Float16 h0 = (_Float16)v.x, h1 = (_Float16)v.y,
                   h2 = (_Float16)v.z, h3 = (_Float16)v.w;
    hh = (f16x4){h0, h1, h2, h3};
    ll = (f16x4){(_Float16)((v.x - (float)h0) * 2048.0f),
                 (_Float16)((v.y - (float)h1) * 2048.0f),
                 (_Float16)((v.z - (float)h2) * 2048.0f),
                 (_Float16)((v.w - (float)h3) * 2048.0f)};
}

// non-draining block barrier: LDS ordering only; vmcnt stays counted.
__device__ __forceinline__ void block_sync_lds() {
    asm volatile("s_waitcnt lgkmcnt(0)" ::: "memory");
    __builtin_amdgcn_s_barrier();
}

__global__ __launch_bounds__(256, 4)
void router_fused(const float* __restrict__ x, const _Float16* __restrict__ wt3,
                  const float* __restrict__ noise,
                  const float* __restrict__ b1, const float* __restrict__ b2,
                  float* __restrict__ out_sparse, float* __restrict__ out_idx,
                  float* __restrict__ out_full) {
    __shared__ __align__(16) _Float16 stage[2][STG_F16];   // 32 KB total
    const int tid  = threadIdx.x;
    const int lane = tid & 63;
    const int wu   = __builtin_amdgcn_readfirstlane(tid >> 6);
    const int col  = lane & 15, q = lane >> 4;   // col = token 0..15
    const long tok0 = (long)blockIdx.x * MTOK;
    const int ta = 2 * wu, tb = 2 * wu + 1;   // this wave's N-tiles

    // staging map: 16 threads/token; thread's j-th float4 (j=0..3) covers
    // chunk cc = j*2 + (fsub>>3), k-group = fsub&7 (k = (fsub&7)*4 ..+3).
    // per-stage float offset of (cc, kgroup): cc*32 + (fsub&7)*4
    //   = j*64 + (fsub>>3)*32 + (fsub&7)*4 = j*64 + fsub*4.
    const int stok = tid >> 4, fsub = tid & 15;
    const float* xs = x + (tok0 + stok) * (size_t)ND + fsub * 4;
    const int g8 = fsub & 7;
    const int wS = g8 >> 1, wh = g8 & 1;

    const _Float16* wla = wt3 + (size_t)ta * 512 + (size_t)lane * 8;
    const _Float16* wlb = wt3 + (size_t)tb * 512 + (size_t)lane * 8;

    f32x4 a0[2], a1[2], zk0[2];
    #pragma unroll
    for (int i = 0; i < 2; ++i)
        #pragma unroll
        for (int r = 0; r < 4; ++r) { a0[i][r] = 0.f; a1[i][r] = 0.f; }

    auto loadX = [&](float4 (&xr)[4], const int s) {
        #pragma unroll
        for (int j = 0; j < 4; ++j)
            xr[j] = *(const float4*)(xs + (size_t)s * XPS + (size_t)j * 64);
    };
    auto deposit = [&](_Float16* wb, const float4 (&xr)[4]) {
        #pragma unroll
        for (int j = 0; j < 4; ++j) {
            const int cc = j * 2 + (fsub >> 3);
            f16x4 hv, lv; split4(xr[j], hv, lv);
            const int idx = ((cc * MTOK + stok) << 6)
                          + (((wS ^ (stok & 7) ^ ((cc & 1) << 2)) << 3) + (wh << 2));
            *(f16x4*)&wb[idx]      = hv;
            *(f16x4*)&wb[idx ^ 32] = lv;
        }
    };

    // one stage: issue B (8 chunks), issue x(s+1) right after (in-flight spans
    // the 48-MFMA section), 8 chunks of ds_read A + 6 MFMA, fold at HSTG-1,
    // deposit, non-draining barrier.
    auto do_stage = [&](const int s, const _Float16* rb, _Float16* wb) {
        f16x8 B[CPSG][4];
        #pragma unroll
        for (int cc = 0; cc < CPSG; ++cc) {
            const size_t cb = (size_t)(s * CPSG + cc) * 8192;
            B[cc][0] = *(const f16x8*)(wla + cb);
            B[cc][1] = *(const f16x8*)(wlb + cb);
            B[cc][2] = *(const f16x8*)(wla + cb + 4096);
            B[cc][3] = *(const f16x8*)(wlb + cb + 4096);
        }
        float4 xl[4];
        if (s + 1 < NSTG) loadX(xl, s + 1);
        #pragma unroll
        for (int cc = 0; cc < CPSG; ++cc) {
            const int swz = (cc & 1) << 2;
            const int ridx = ((cc * MTOK + col) << 6)
                           + ((q ^ (col & 7) ^ swz) << 3);
            const f16x8 ah = *(const f16x8*)&rb[ridx];
            const f16x8 al = *(const f16x8*)&rb[ridx ^ 32];
            // per-accumulator chain order identical to R6..R11
            a0[0] = __builtin_amdgcn_mfma_f32_16x16x32_f16(ah, B[cc][0], a0[0], 0, 0, 0);
            a0[1] = __builtin_amdgcn_mfma_f32_16x16x32_f16(ah, B[cc][1], a0[1], 0, 0, 0);
            a1[0] = __builtin_amdgcn_mfma_f32_16x16x32_f16(ah, B[cc][2], a1[0], 0, 0, 0);
            a1[1] = __builtin_amdgcn_mfma_f32_16x16x32_f16(ah, B[cc][3], a1[1], 0, 0, 0);
            a1[0] = __builtin_amdgcn_mfma_f32_16x16x32_f16(al, B[cc][0], a1[0], 0, 0, 0);
            a1[1] = __builtin_amdgcn_mfma_f32_16x16x32_f16(al, B[cc][1], a1[1], 0, 0, 0);
        }
        if (s == HSTG - 1) {   // chunks 0..31 done: fold seg-0 partial, reset acc
            #pragma unroll
            for (int i = 0; i < 2; ++i) {
                zk0[i] = a0[i] + a1[i] * 4.8828125e-4f;
                #pragma unroll
                for (int r = 0; r < 4; ++r) { a0[i][r] = 0.f; a1[i][r] = 0.f; }
            }
        }
        if (s + 1 < NSTG) deposit(wb, xl);
        block_sync_lds();
    };

    // prologue: stage-0 deposit
    {
        float4 x0[4];
        loadX(x0, 0);
        deposit(stage[0], x0);
    }
    block_sync_lds();

    // main loop, unrolled x2: buffers compile-time (8 stages -> 4 iterations)
    for (int sp = 0; sp < NSTG; sp += 2) {
        do_stage(sp,     stage[0], stage[1]);
        do_stage(sp + 1, stage[1], stage[0]);
    }

    // seg-1 fold + f64 combine, stage z-tile to LDS (aliases stage bufs; all
    // frag reads completed at the final stage barrier).
    float* zs = (float*)&stage[0][0];   // 16*132*4 = 8448 B <= 16 KB
    #pragma unroll
    for (int i = 0; i < 2; ++i) {
        const int n = (ta + i) * 16 + col;
        #pragma unroll
        for (int r = 0; r < 4; ++r) {
            const float zk1 = a0[i][r] + a1[i][r] * 4.8828125e-4f;
            const float comb = (float)((double)zk0[i][r] + (double)zk1);
            zs[(q * 4 + r) * ZROW + n] = comb;
        }
    }
    __syncthreads();

    // ---- epilogue: softplus, softmax/top8/masked softmax (verbatim; 4 tok/wave).
    const float b1v = b1[lane];
    const float b2v = b2[lane];
    for (int tt = 0; tt < 4; ++tt) {
        const int lt = wu * 4 + tt;
        const long tok = tok0 + lt;
        const float z1 = zs[lt * ZROW + lane] + b1v;
        const float z2 = zs[lt * ZROW + 64 + lane] + b2v;
        const float sc = (float)log1p(exp((double)z2));   // f64 softplus
        const float nz = noise[tok * NE + lane];
        const float mixed = z1 + nz * sc;

        float vmax = mixed;
        for (int off = 32; off; off >>= 1) vmax = fmaxf(vmax, __shfl_xor(vmax, off));
        const float e = expf(mixed - vmax);
        float denom = e;
        for (int off = 32; off; off >>= 1) denom += __shfl_xor(denom, off);
        const float fullv = e / denom;

        float cur = mixed;
        int   sel = 0;
        float myidxf = 0.0f;
        #pragma unroll
        for (int r = 0; r < NK; ++r) {
            float bv = cur; int bi = lane;
            for (int off = 32; off; off >>= 1) {
                const float ov = __shfl_xor(bv, off);
                const int   oi = __shfl_xor(bi, off);
                if (ov > bv || (ov == bv && oi < bi)) { bv = ov; bi = oi; }
            }
            if (lane == r)  myidxf = (float)bi;
            if (lane == bi) { sel = 1; cur = -INFINITY; }
        }

        const float es = sel ? e : 0.0f;
        float dsum = es;
        for (int off = 32; off; off >>= 1) dsum += __shfl_xor(dsum, off);
        const float sparsev = sel ? (e / dsum) : 0.0f;

        out_full[tok * NE + lane]   = fullv;
        out_sparse[tok * NE + lane] = sparsev;
        if (lane < NK) out_idx[tok * NK + lane] = myidxf;
    }
}

extern "C" void kernel_launch(void* const* d_in, const int* in_sizes, int n_in,
                              void* d_out, int out_size, void* d_ws, size_t ws_size,
                              hipStream_t stream) {
    const float* x     = (const float*)d_in[0];
    const float* noise = (const float*)d_in[1];
    const float* W1    = (const float*)d_in[2];
    const float* b1    = (const float*)d_in[3];
    const float* W2    = (const float*)d_in[4];
    const float* b2    = (const float*)d_in[5];

    float* out_sparse = (float*)d_out;                      // [16384*64]
    float* out_idx    = out_sparse + (size_t)NTOK * NE;     // [16384*8]
    float* out_full   = out_idx + (size_t)NTOK * NK;        // [16384*64]

    _Float16* wt3 = (_Float16*)d_ws;                        // 1 MB fragment-order W

    prep_w<<<128, 256, 0, stream>>>(W1, W2, wt3);
    router_fused<<<NTOK / MTOK, 256, 0, stream>>>(x, wt3, noise, b1, b2,
                                                  out_sparse, out_idx, out_full);   // 1024 blocks
}